// Round 1
// baseline (602.265 us; speedup 1.0000x reference)
//
#include <hip/hip_runtime.h>

// DGM forward, MI355X. bf16 MFMA (16x16x32), fp32 accum, fp32 tanh.
// Layout notes:
//  - A-frag (16x16x32): lane holds A[m=ln&15][k=kb*32+(ln>>4)*8+i], i=0..7
//  - B-frag:            lane holds B[k=kb*32+(ln>>4)*8+i][n=c*16+(ln&15)]
//  - C/D:               lane holds C[row=(ln>>4)*4+i][col=ln&15]
// W pre-packed in d_ws in B-frag order: idx = (((c*8+kb)*64+ln)*8+i)
// LDS state buffers use XOR chunk swizzle: elem(r,k) -> r*256 + (((k>>3)^r)&31)*8 + (k&7)

typedef __attribute__((ext_vector_type(8))) short bf16x8;
typedef __attribute__((ext_vector_type(4))) float f32x4;

__device__ __forceinline__ short f2bf(float f) {
    unsigned u = __float_as_uint(f);
    unsigned r = (u + 0x7FFFu + ((u >> 16) & 1u)) >> 16;
    return (short)r;
}
__device__ __forceinline__ float bf2f(short h) {
    return __uint_as_float(((unsigned)(unsigned short)h) << 16);
}
__device__ __forceinline__ float fast_tanh(float x) {
    // tanh(x) = 1 - 2/(exp(2x)+1); exact at +-inf, ~1e-6 rel err
    float e = __expf(2.0f * x);
    return 1.0f - 2.0f * __builtin_amdgcn_rcpf(e + 1.0f);
}
__device__ __forceinline__ int sw_idx(int r, int k) {
    return r * 256 + ((((k >> 3) ^ r) & 31) << 3) + (k & 7);
}

// ---------------- pack weights fp32 -> bf16, B-fragment order ----------------
__global__ void pack_w(const float* __restrict__ Wz, const float* __restrict__ Wg,
                       const float* __restrict__ Wr, const float* __restrict__ Wh,
                       short* __restrict__ out) {
    int idx = blockIdx.x * 256 + threadIdx.x;   // 12*65536 threads
    int mat = idx >> 16;                        // 0..11 = l*4+g
    int e   = idx & 65535;
    int l = mat >> 2, g = mat & 3;
    int i  = e & 7;
    int ln = (e >> 3) & 63;
    int kb = (e >> 9) & 7;
    int c  = e >> 12;
    int k = kb * 32 + (ln >> 4) * 8 + i;
    int n = c * 16 + (ln & 15);
    const float* W = (g == 0) ? Wz : (g == 1) ? Wg : (g == 2) ? Wr : Wh;
    out[idx] = f2bf(W[l * 65536 + k * 256 + n]);
}

// ---------------- one gate GEMM: acc = bias + X@U + In@W ----------------
__device__ __forceinline__ void gate_gemm(const short* __restrict__ In,   // LDS, swizzled [32][256]
                                          const short* __restrict__ Wm,   // packed bf16 65536
                                          const float* __restrict__ U,    // [2][256]
                                          const float* __restrict__ bias, // [256]
                                          const float* tv, const float* xv,
                                          int q, int c15, int w, f32x4 acc[2][4]) {
#pragma unroll
    for (int cb = 0; cb < 4; cb++) {
        int col = (w * 4 + cb) * 16 + c15;
        float u0 = U[col], u1 = U[256 + col], bb = bias[col];
#pragma unroll
        for (int rb = 0; rb < 2; rb++)
#pragma unroll
            for (int ii = 0; ii < 4; ii++)
                acc[rb][cb][ii] = bb + tv[rb * 4 + ii] * u0 + xv[rb * 4 + ii] * u1;
    }
#pragma unroll
    for (int kb = 0; kb < 8; kb++) {
        bf16x8 a[2];
#pragma unroll
        for (int rb = 0; rb < 2; rb++) {
            int r = rb * 16 + c15;                       // A row = ln&15
            int off = r * 256 + (((kb * 4 + q) ^ r) & 31) * 8;
            a[rb] = *(const bf16x8*)(In + off);
        }
#pragma unroll
        for (int cb = 0; cb < 4; cb++) {
            bf16x8 b = *(const bf16x8*)(Wm + ((((w * 4 + cb) * 8 + kb) * 64) + (q * 16 + c15)) * 8);
#pragma unroll
            for (int rb = 0; rb < 2; rb++)
                acc[rb][cb] = __builtin_amdgcn_mfma_f32_16x16x32_bf16(a[rb], b, acc[rb][cb], 0, 0, 0);
        }
    }
}

// ---------------- main kernel: 32 rows per WG, 256 threads ----------------
__launch_bounds__(256, 2)
__global__ void dgm_main(const float* __restrict__ T, const float* __restrict__ X,
                         const float* __restrict__ W0, const float* __restrict__ b0,
                         const float* __restrict__ Uz, const float* __restrict__ Ug,
                         const float* __restrict__ Ur, const float* __restrict__ Uh,
                         const float* __restrict__ bz, const float* __restrict__ bg,
                         const float* __restrict__ br, const float* __restrict__ bh,
                         const float* __restrict__ Wf, const float* __restrict__ bfp,
                         const short* __restrict__ Wp, float* __restrict__ out) {
    __shared__ __align__(16) short Sb[8192];
    __shared__ __align__(16) short S1b[8192];
    __shared__ __align__(16) short SRb[8192];
    __shared__ float tS[32], xS[32];

    const int tid = threadIdx.x;
    const int w   = tid >> 6;
    const int ln  = tid & 63;
    const int q   = ln >> 4;
    const int c15 = ln & 15;
    const int m0  = blockIdx.x * 32;

    if (tid < 32) tS[tid] = T[m0 + tid];
    else if (tid < 64) xS[tid - 32] = X[m0 + tid - 32];
    __syncthreads();

    // ---- S1 = tanh(X@W0 + b0); S = S1 ----
    {
        int j = tid;
        float w00 = W0[j], w01 = W0[256 + j], bb = b0[j];
#pragma unroll 4
        for (int r = 0; r < 32; r++) {
            short v = f2bf(fast_tanh(tS[r] * w00 + xS[r] * w01 + bb));
            int off = sw_idx(r, j);
            S1b[off] = v;
            Sb[off]  = v;
        }
    }
    __syncthreads();

    // per-thread row t/x values (rows rb*16 + q*4 + ii)
    float tv[8], xv[8];
#pragma unroll
    for (int rb = 0; rb < 2; rb++)
#pragma unroll
        for (int ii = 0; ii < 4; ii++) {
            int r = rb * 16 + q * 4 + ii;
            tv[rb * 4 + ii] = tS[r];
            xv[rb * 4 + ii] = xS[r];
        }

    // ---- layers ----
    for (int l = 0; l < 3; l++) {
        const short* Wzp = Wp + (l * 4 + 0) * 65536;
        const short* Wgp = Wp + (l * 4 + 1) * 65536;
        const short* Wrp = Wp + (l * 4 + 2) * 65536;
        const short* Whp = Wp + (l * 4 + 3) * 65536;

        f32x4 zacc[2][4], gacc[2][4], racc[2][4];
        gate_gemm(Sb,  Wzp, Uz + l * 512, bz + l * 256, tv, xv, q, c15, w, zacc);
        gate_gemm(S1b, Wgp, Ug + l * 512, bg + l * 256, tv, xv, q, c15, w, gacc);
        gate_gemm(Sb,  Wrp, Ur + l * 512, br + l * 256, tv, xv, q, c15, w, racc);

        // tanh Z,G in place; R -> SR = S*R into LDS
#pragma unroll
        for (int rb = 0; rb < 2; rb++)
#pragma unroll
            for (int cb = 0; cb < 4; cb++)
#pragma unroll
                for (int ii = 0; ii < 4; ii++) {
                    int row = rb * 16 + q * 4 + ii;
                    int col = (w * 4 + cb) * 16 + c15;
                    zacc[rb][cb][ii] = fast_tanh(zacc[rb][cb][ii]);
                    gacc[rb][cb][ii] = fast_tanh(gacc[rb][cb][ii]);
                    float r = fast_tanh(racc[rb][cb][ii]);
                    int off = sw_idx(row, col);
                    SRb[off] = f2bf(bf2f(Sb[off]) * r);
                }
        __syncthreads();   // SR complete

        f32x4 hacc[2][4];
        gate_gemm(SRb, Whp, Uh + l * 512, bh + l * 256, tv, xv, q, c15, w, hacc);

        // S = (1-G)*H + Z*S  (each element owned by exactly one thread)
#pragma unroll
        for (int rb = 0; rb < 2; rb++)
#pragma unroll
            for (int cb = 0; cb < 4; cb++)
#pragma unroll
                for (int ii = 0; ii < 4; ii++) {
                    int row = rb * 16 + q * 4 + ii;
                    int col = (w * 4 + cb) * 16 + c15;
                    float h = fast_tanh(hacc[rb][cb][ii]);
                    int off = sw_idx(row, col);
                    float s = bf2f(Sb[off]);
                    float sn = (1.0f - gacc[rb][cb][ii]) * h + zacc[rb][cb][ii] * s;
                    Sb[off] = f2bf(sn);
                }
        __syncthreads();   // S complete for next layer
    }

    // ---- out = S @ Wf + bf : 8 threads per row ----
    {
        int row = tid >> 3;
        int seg = tid & 7;
        float sum = 0.0f;
#pragma unroll 8
        for (int kk = 0; kk < 32; kk++) {
            int k = seg * 32 + kk;
            sum += bf2f(Sb[sw_idx(row, k)]) * Wf[k];
        }
        sum += __shfl_down(sum, 4, 8);
        sum += __shfl_down(sum, 2, 8);
        sum += __shfl_down(sum, 1, 8);
        if (seg == 0) out[m0 + row] = sum + bfp[0];
    }
}

extern "C" void kernel_launch(void* const* d_in, const int* in_sizes, int n_in,
                              void* d_out, int out_size, void* d_ws, size_t ws_size,
                              hipStream_t stream) {
    const float* T  = (const float*)d_in[0];
    const float* X  = (const float*)d_in[1];
    const float* W0 = (const float*)d_in[2];
    const float* b0 = (const float*)d_in[3];
    const float* Uz = (const float*)d_in[4];
    const float* Ug = (const float*)d_in[5];
    const float* Ur = (const float*)d_in[6];
    const float* Uh = (const float*)d_in[7];
    const float* Wz = (const float*)d_in[8];
    const float* Wg = (const float*)d_in[9];
    const float* Wr = (const float*)d_in[10];
    const float* Wh = (const float*)d_in[11];
    const float* bz = (const float*)d_in[12];
    const float* bg = (const float*)d_in[13];
    const float* br = (const float*)d_in[14];
    const float* bh = (const float*)d_in[15];
    const float* Wf = (const float*)d_in[16];
    const float* bfp= (const float*)d_in[17];
    float* out = (float*)d_out;
    short* Wp = (short*)d_ws;           // 12*65536 bf16 = 1.5 MB
    const int N = in_sizes[0];

    pack_w<<<(12 * 65536) / 256, 256, 0, stream>>>(Wz, Wg, Wr, Wh, Wp);
    dgm_main<<<N / 32, 256, 0, stream>>>(T, X, W0, b0, Uz, Ug, Ur, Uh,
                                         bz, bg, br, bh, Wf, bfp, Wp, out);
}